// Round 3
// baseline (381.395 us; speedup 1.0000x reference)
//
#include <hip/hip_runtime.h>
#include <hip/hip_bf16.h>
#include <stdint.h>

// Round 3: FIX — d_out is fp32 (reference output dtype), not bf16.
// Also: q_tok / Qp intermediates live in d_out's two 25 MB halves (f16),
// attention O in ws; ws footprint 37 MB.
// Structure otherwise identical to round 2 (plain LDS, padded rows, MFMA f16).

typedef _Float16 f16;
typedef _Float16 f16x8 __attribute__((ext_vector_type(8)));
typedef float f32x4 __attribute__((ext_vector_type(4)));
typedef uint32_t u32;

#define NC 384
#define MFMA16(A_,B_,C_) __builtin_amdgcn_mfma_f32_16x16x32_f16((A_),(B_),(C_),0,0,0)

// ---------------- weight fp32 -> f16 convert ----------------
__global__ __launch_bounds__(256) void cvt_w(
    const float* __restrict__ s0, const float* __restrict__ s1,
    const float* __restrict__ s2, const float* __restrict__ s3,
    f16* __restrict__ d0, f16* __restrict__ d1,
    f16* __restrict__ d2, f16* __restrict__ d3, int n)
{
  int i = blockIdx.x * 256 + threadIdx.x;
  if (i < n) { d0[i] = (f16)s0[i]; d1[i] = (f16)s1[i]; d2[i] = (f16)s2[i]; d3[i] = (f16)s3[i]; }
}

// ---------------- depthwise conv3d (k=3,p=1,stride S) + BN -> f16 tokens ----------------
template<int S>
__global__ __launch_bounds__(384) void conv_bn(
    const float* __restrict__ x, const float* __restrict__ wgt,
    const float* __restrict__ bg, const float* __restrict__ bb_,
    const float* __restrict__ bm, const float* __restrict__ bv,
    f16* __restrict__ out)
{
  const int E = 16 / S;
  const int c = threadIdx.x;
  const int hw = blockIdx.x;
  const int b = blockIdx.y;
  const int hh = hw / E, ww = hw % E;
  __shared__ float wl[NC * 27];
  for (int idx = c; idx < NC * 27; idx += NC) wl[idx] = wgt[idx];
  __syncthreads();
  const float inv = bg[c] * rsqrtf(bv[c] + 1e-5f);
  const float beta = bb_[c] - bm[c] * inv;
  float wr[27];
#pragma unroll
  for (int t = 0; t < 27; ++t) wr[t] = wl[c * 27 + t];
  const int ih0 = hh * S - 1, iw0 = ww * S - 1;
  for (int dd = 0; dd < E; ++dd) {
    const int id0 = dd * S - 1;
    float acc = 0.f;
#pragma unroll
    for (int dh = 0; dh < 3; ++dh) {
      const int ih = ih0 + dh;
      if ((unsigned)ih >= 16u) continue;
#pragma unroll
      for (int dw = 0; dw < 3; ++dw) {
        const int iw = iw0 + dw;
        if ((unsigned)iw >= 16u) continue;
#pragma unroll
        for (int dz = 0; dz < 3; ++dz) {
          const int id = id0 + dz;
          if ((unsigned)id >= 16u) continue;
          acc += x[((size_t)b * 4096 + ih * 256 + iw * 16 + id) * NC + c] * wr[(dh * 3 + dw) * 3 + dz];
        }
      }
    }
    out[((size_t)b * (E * E * E) + (hh * E + ww) * E + dd) * NC + c] = (f16)(acc * inv + beta);
  }
}

// ---------------- GEMM: C[M,384] = A[M,384] * W[384,384]^T ----------------
// 128x128 tile, BK=64, 4 waves (each 64x64). Plain reg-staged LDS, padded rows.
// MODE 0: f16 out; MODE 1: f16 transposed out C[b][col][t]; MODE 2: fp32 out + bias.
template<int MODE>
__global__ __launch_bounds__(256) void gemm_bt(
    const f16* __restrict__ A, const f16* __restrict__ Bw,
    void* __restrict__ Cout, const float* __restrict__ bias)
{
  const int LDT = 72;  // 64 data + 8 pad (row stride 144 B, 16B-aligned)
  __shared__ f16 As[128 * 72];
  __shared__ f16 Bs[128 * 72];
  const int tid = threadIdx.x;
  const int w = tid >> 6, lane = tid & 63;
  const int g = lane >> 4, q = lane & 15;
  const int wr = w >> 1, wc = w & 1;
  const size_t brow = (size_t)blockIdx.y * 128;
  const int bcol = blockIdx.x * 128;
  f32x4 acc[4][4] = {};
  for (int kt = 0; kt < 6; ++kt) {
    const int k0 = kt * 64;
    __syncthreads();  // previous iter's readers done before re-stage
#pragma unroll
    for (int i = tid; i < 1024; i += 256) {
      const int row = i >> 3, blk = i & 7;
      *(f16x8*)&As[row * LDT + blk * 8] = *(const f16x8*)&A[(brow + row) * NC + k0 + blk * 8];
      *(f16x8*)&Bs[row * LDT + blk * 8] = *(const f16x8*)&Bw[((size_t)bcol + row) * NC + k0 + blk * 8];
    }
    __syncthreads();
#pragma unroll
    for (int ks = 0; ks < 2; ++ks) {
      f16x8 af[4], bfr[4];
#pragma unroll
      for (int m = 0; m < 4; ++m) {
        af[m]  = *(const f16x8*)&As[(wr * 64 + m * 16 + q) * LDT + (4 * ks + g) * 8];
        bfr[m] = *(const f16x8*)&Bs[(wc * 64 + m * 16 + q) * LDT + (4 * ks + g) * 8];
      }
#pragma unroll
      for (int m = 0; m < 4; ++m)
#pragma unroll
        for (int n = 0; n < 4; ++n)
          acc[m][n] = MFMA16(af[m], bfr[n], acc[m][n]);
    }
  }
  float bvals[4];
  if (MODE == 2) {
#pragma unroll
    for (int n = 0; n < 4; ++n) bvals[n] = bias[bcol + wc * 64 + n * 16 + q];
  }
#pragma unroll
  for (int m = 0; m < 4; ++m) {
#pragma unroll
    for (int n = 0; n < 4; ++n) {
#pragma unroll
      for (int r = 0; r < 4; ++r) {
        const size_t row = brow + wr * 64 + m * 16 + 4 * g + r;
        const int col = bcol + wc * 64 + n * 16 + q;
        const float v = acc[m][n][r];
        if (MODE == 0) {
          ((f16*)Cout)[row * NC + col] = (f16)v;
        } else if (MODE == 1) {
          const size_t bi = row >> 9, t = row & 511;
          ((f16*)Cout)[(bi * NC + col) * 512 + t] = (f16)v;
        } else {
          ((float*)Cout)[row * NC + col] = v + bvals[n];
        }
      }
    }
  }
}

// ---------------- flash attention (LDS P round-trip) ----------------
// grid (32 qtiles, 6 heads, 8 batch); 512 thr = 8 waves, each wave owns 16 q-rows.
__global__ __launch_bounds__(512) void attn(
    const f16* __restrict__ Qp, const f16* __restrict__ Kp,
    const f16* __restrict__ Vt, f16* __restrict__ O)
{
  const int LK = 72;    // K row stride  (64 d + 8)
  const int LV = 136;   // V row stride  (128 j + 8)
  const int LP = 136;   // P row stride  (128 j + 8)
  __shared__ f16 Ks[128 * 72];       // [j][d]
  __shared__ f16 Vs[64 * 136];       // [dh][j]
  __shared__ f16 Ps[8 * 16 * 136];   // [wave][q][j]
  const int tid = threadIdx.x;
  const int w = tid >> 6, lane = tid & 63;
  const int g = lane >> 4, q = lane & 15;
  const int qt = blockIdx.x, h = blockIdx.y, b = blockIdx.z;
  const float sc = 0.051031036307982884f * 1.4426950408889634f; // 384^-0.5 * log2(e)
  const size_t qrow0 = (size_t)b * 4096 + qt * 128 + w * 16;
  f16x8 qf[2];
#pragma unroll
  for (int ks = 0; ks < 2; ++ks)
    qf[ks] = *(const f16x8*)(Qp + (qrow0 + q) * NC + h * 64 + ks * 32 + g * 8);
  f32x4 oa[4] = {};
  float m_run = -INFINITY, l_run = 0.f;
  for (int ch = 0; ch < 4; ++ch) {
    const size_t kb = (size_t)b * 512 + ch * 128;
    __syncthreads();  // previous chunk's readers done
#pragma unroll
    for (int i = tid; i < 1024; i += 512) {   // K: 128 rows x 8 blks
      const int j = i >> 3, blk = i & 7;
      *(f16x8*)&Ks[j * LK + blk * 8] = *(const f16x8*)&Kp[(kb + j) * NC + h * 64 + blk * 8];
    }
#pragma unroll
    for (int i = tid; i < 1024; i += 512) {   // V: 64 rows x 16 blks
      const int dh = i >> 4, blk = i & 15;
      *(f16x8*)&Vs[dh * LV + blk * 8] =
          *(const f16x8*)&Vt[((size_t)b * NC + h * 64 + dh) * 512 + ch * 128 + blk * 8];
    }
    __syncthreads();
    // S^T = K (128xj,64d) x Q^T : lane owns q-row (col=q), j = m*16 + 4g + r
    f32x4 st[8] = {};
#pragma unroll
    for (int ks = 0; ks < 2; ++ks) {
#pragma unroll
      for (int m = 0; m < 8; ++m) {
        const f16x8 kf = *(const f16x8*)&Ks[(m * 16 + q) * LK + (4 * ks + g) * 8];
        st[m] = MFMA16(kf, qf[ks], st[m]);
      }
    }
    // online softmax
    float tv[8][4];
    float cmax = -INFINITY;
#pragma unroll
    for (int m = 0; m < 8; ++m)
#pragma unroll
      for (int r = 0; r < 4; ++r) { tv[m][r] = st[m][r] * sc; cmax = fmaxf(cmax, tv[m][r]); }
    cmax = fmaxf(cmax, __shfl_xor(cmax, 16));
    cmax = fmaxf(cmax, __shfl_xor(cmax, 32));
    const float mnew = fmaxf(m_run, cmax);
    const float fac = exp2f(m_run - mnew);
    float psum = 0.f;
#pragma unroll
    for (int m = 0; m < 8; ++m) {
      const float p0 = exp2f(tv[m][0] - mnew), p1 = exp2f(tv[m][1] - mnew);
      const float p2 = exp2f(tv[m][2] - mnew), p3 = exp2f(tv[m][3] - mnew);
      psum += (p0 + p1) + (p2 + p3);
      f16* pr = &Ps[(w * 16 + q) * LP + m * 16 + 4 * g];
      pr[0] = (f16)p0; pr[1] = (f16)p1; pr[2] = (f16)p2; pr[3] = (f16)p3;
    }
    psum += __shfl_xor(psum, 16);
    psum += __shfl_xor(psum, 32);
    l_run = l_run * fac + psum;
    m_run = mnew;
    // rescale O (O row = 4g+r; factor for q-row i lives at lane i)
#pragma unroll
    for (int r = 0; r < 4; ++r) {
      const float fr = __shfl(fac, g * 4 + r);
#pragma unroll
      for (int n = 0; n < 4; ++n) oa[n][r] *= fr;
    }
    __syncthreads();  // Ps visible
    // PV: O[i][dh] += P[i][j] V[j][dh]
#pragma unroll
    for (int ks = 0; ks < 4; ++ks) {
      const f16x8 pa = *(const f16x8*)&Ps[(w * 16 + q) * LP + ks * 32 + g * 8];
#pragma unroll
      for (int n = 0; n < 4; ++n) {
        const f16x8 vf = *(const f16x8*)&Vs[(n * 16 + q) * LV + ks * 32 + g * 8];
        oa[n] = MFMA16(pa, vf, oa[n]);
      }
    }
  }
  const float linv = 1.0f / l_run;
#pragma unroll
  for (int r = 0; r < 4; ++r) {
    const float lr = __shfl(linv, g * 4 + r);
    const size_t row = qrow0 + 4 * g + r;
#pragma unroll
    for (int n = 0; n < 4; ++n)
      O[row * NC + h * 64 + n * 16 + q] = (f16)(oa[n][r] * lr);
  }
}

// ---------------- launch ----------------
extern "C" void kernel_launch(void* const* d_in, const int* in_sizes, int n_in,
                              void* d_out, int out_size, void* d_ws, size_t ws_size,
                              hipStream_t stream) {
  const float* x   = (const float*)d_in[0];
  const float* cqw = (const float*)d_in[1];
  const float* ckw = (const float*)d_in[2];
  const float* cvw = (const float*)d_in[3];
  const float* bqg = (const float*)d_in[4],  *bqb = (const float*)d_in[5];
  const float* bqm = (const float*)d_in[6],  *bqv = (const float*)d_in[7];
  const float* bkg = (const float*)d_in[8],  *bkb = (const float*)d_in[9];
  const float* bkm = (const float*)d_in[10], *bkv = (const float*)d_in[11];
  const float* bvg = (const float*)d_in[12], *bvb = (const float*)d_in[13];
  const float* bvm = (const float*)d_in[14], *bvv = (const float*)d_in[15];
  const float* wq = (const float*)d_in[16];
  const float* wk = (const float*)d_in[17];
  const float* wv = (const float*)d_in[18];
  const float* pw = (const float*)d_in[19];
  const float* pb = (const float*)d_in[20];

  // d_out is fp32: 12,582,912 floats = 50,331,648 B. Use its two 25 MB halves
  // as f16 scratch for q_tok (lo) and Qp (hi) until the final GEMM overwrites it.
  f16* q_tok = (f16*)d_out;                              // 25,165,824 B
  f16* Qp    = (f16*)((char*)d_out + 25165824);          // 25,165,824 B

  char* ws = (char*)d_ws;
  f16* wq_h  = (f16*)(ws + 0);
  f16* wk_h  = (f16*)(ws + 294912);
  f16* wv_h  = (f16*)(ws + 589824);
  f16* pw_h  = (f16*)(ws + 884736);
  f16* k_tok = (f16*)(ws + 1179648);    // 3,145,728 B
  f16* v_tok = (f16*)(ws + 4325376);    // 3,145,728 B
  f16* Kp    = (f16*)(ws + 7471104);    // 3,145,728 B
  f16* Vt    = (f16*)(ws + 10616832);   // 3,145,728 B
  f16* Oi    = (f16*)(ws + 13762560);   // 25,165,824 B ; ws total 38,928,384 B

  cvt_w<<<dim3(576), dim3(256), 0, stream>>>(wq, wk, wv, pw, wq_h, wk_h, wv_h, pw_h, 147456);
  conv_bn<1><<<dim3(256, 8), dim3(384), 0, stream>>>(x, cqw, bqg, bqb, bqm, bqv, q_tok);
  conv_bn<2><<<dim3(64, 8),  dim3(384), 0, stream>>>(x, ckw, bkg, bkb, bkm, bkv, k_tok);
  conv_bn<2><<<dim3(64, 8),  dim3(384), 0, stream>>>(x, cvw, bvg, bvb, bvm, bvv, v_tok);
  gemm_bt<0><<<dim3(3, 256), dim3(256), 0, stream>>>(q_tok, wq_h, Qp, nullptr);  // lo->hi, disjoint
  gemm_bt<0><<<dim3(3, 32),  dim3(256), 0, stream>>>(k_tok, wk_h, Kp, nullptr);
  gemm_bt<1><<<dim3(3, 32),  dim3(256), 0, stream>>>(v_tok, wv_h, Vt, nullptr);
  attn<<<dim3(32, 6, 8), dim3(512), 0, stream>>>(Qp, Kp, Vt, Oi);
  gemm_bt<2><<<dim3(3, 256), dim3(256), 0, stream>>>(Oi, pw_h, d_out, pb);       // fp32 + bias
}

// Round 4
// 194.588 us; speedup vs baseline: 1.9600x; 1.9600x over previous
//
#include <hip/hip_runtime.h>
#include <hip/hip_bf16.h>
#include <stdint.h>

// Round 4: fuse the three depthwise convs into one x-pass with a register
// z-ring window (4 taps/output instead of 27; x read 1x instead of 3x).
// Rest identical to round 3 (passing, absmax 4.9e-4).

typedef _Float16 f16;
typedef _Float16 f16x8 __attribute__((ext_vector_type(8)));
typedef float f32x4 __attribute__((ext_vector_type(4)));
typedef uint32_t u32;

#define NC 384
#define MFMA16(A_,B_,C_) __builtin_amdgcn_mfma_f32_16x16x32_f16((A_),(B_),(C_),0,0,0)

// ---------------- weight fp32 -> f16 convert ----------------
__global__ __launch_bounds__(256) void cvt_w(
    const float* __restrict__ s0, const float* __restrict__ s1,
    const float* __restrict__ s2, const float* __restrict__ s3,
    f16* __restrict__ d0, f16* __restrict__ d1,
    f16* __restrict__ d2, f16* __restrict__ d3, int n)
{
  int i = blockIdx.x * 256 + threadIdx.x;
  if (i < n) { d0[i] = (f16)s0[i]; d1[i] = (f16)s1[i]; d2[i] = (f16)s2[i]; d3[i] = (f16)s3[i]; }
}

// ---------------- fused depthwise conv3d + BN for q(s=1), k(s=2), v(s=2) ----------------
// 384 thr = channel; grid (64 hw-tiles, 8 b). 2x2 (h,w) tile at (2*th, 2*tw);
// z-stream with 3-plane ring window win[3][4][4] (fully unrolled -> static regs).
__global__ __launch_bounds__(384) void conv_fused(
    const float* __restrict__ x,
    const float* __restrict__ wq_, const float* __restrict__ wk_, const float* __restrict__ wv_,
    const float* __restrict__ bqg, const float* __restrict__ bqb,
    const float* __restrict__ bqm, const float* __restrict__ bqv,
    const float* __restrict__ bkg, const float* __restrict__ bkb,
    const float* __restrict__ bkm, const float* __restrict__ bkv,
    const float* __restrict__ bvg, const float* __restrict__ bvb,
    const float* __restrict__ bvm, const float* __restrict__ bvv,
    f16* __restrict__ qout, f16* __restrict__ kout, f16* __restrict__ vout)
{
  const int c = threadIdx.x;
  const int th = blockIdx.x >> 3, tw = blockIdx.x & 7;
  const int b = blockIdx.y;
  const int h0 = th * 2, w0 = tw * 2;

  float wqr[27], wkr[27], wvr[27];
#pragma unroll
  for (int t = 0; t < 27; ++t) {
    wqr[t] = wq_[c * 27 + t];
    wkr[t] = wk_[c * 27 + t];
    wvr[t] = wv_[c * 27 + t];
  }
  const float invq = bqg[c] * rsqrtf(bqv[c] + 1e-5f), betq = bqb[c] - bqm[c] * invq;
  const float invk = bkg[c] * rsqrtf(bkv[c] + 1e-5f), betk = bkb[c] - bkm[c] * invk;
  const float invv = bvg[c] * rsqrtf(bvv[c] + 1e-5f), betv = bvb[c] - bvm[c] * invv;

  bool hok[4], wok[4];
#pragma unroll
  for (int a = 0; a < 4; ++a) {
    hok[a] = (unsigned)(h0 - 1 + a) < 16u;   // block-uniform
    wok[a] = (unsigned)(w0 - 1 + a) < 16u;
  }
  const float* xb = x + (size_t)b * 4096 * NC + c;

  float win[3][4][4];
  auto ldplane = [&](int s, int iz) {   // s, iz compile-time after inlining
#pragma unroll
    for (int a = 0; a < 4; ++a)
#pragma unroll
      for (int e = 0; e < 4; ++e) {
        float v = 0.f;
        if (hok[a] && wok[e])
          v = xb[(size_t)((h0 - 1 + a) * 256 + (w0 - 1 + e) * 16 + iz) * NC];
        win[s][a][e] = v;
      }
  };
  // prologue: plane iz=-1 (slot 2) = zeros; plane iz=0 -> slot 0
#pragma unroll
  for (int a = 0; a < 4; ++a)
#pragma unroll
    for (int e = 0; e < 4; ++e) win[2][a][e] = 0.f;
  ldplane(0, 0);

#pragma unroll
  for (int z = 0; z < 16; ++z) {
    const int snew = (z + 1) % 3;
    if (z + 1 < 16) {
      ldplane(snew, z + 1);
    } else {
#pragma unroll
      for (int a = 0; a < 4; ++a)
#pragma unroll
        for (int e = 0; e < 4; ++e) win[snew][a][e] = 0.f;
    }
    float aq00 = 0.f, aq01 = 0.f, aq10 = 0.f, aq11 = 0.f;
    float ak = 0.f, av = 0.f;
#pragma unroll
    for (int p = 0; p < 3; ++p) {
      const int s = (z - 1 + p + 3) % 3;
#pragma unroll
      for (int a = 0; a < 3; ++a)
#pragma unroll
        for (int e = 0; e < 3; ++e) {
          const float w00 = win[s][a][e],     w01 = win[s][a][e + 1];
          const float w10 = win[s][a + 1][e], w11 = win[s][a + 1][e + 1];
          const float cq = wqr[a * 9 + e * 3 + p];
          aq00 += w00 * cq; aq01 += w01 * cq;
          aq10 += w10 * cq; aq11 += w11 * cq;
          if ((z & 1) == 0) {
            ak += w00 * wkr[a * 9 + e * 3 + p];
            av += w00 * wvr[a * 9 + e * 3 + p];
          }
        }
    }
    const size_t qb = (size_t)b * 4096;
    qout[(qb + (h0 + 0) * 256 + (w0 + 0) * 16 + z) * NC + c] = (f16)(aq00 * invq + betq);
    qout[(qb + (h0 + 0) * 256 + (w0 + 1) * 16 + z) * NC + c] = (f16)(aq01 * invq + betq);
    qout[(qb + (h0 + 1) * 256 + (w0 + 0) * 16 + z) * NC + c] = (f16)(aq10 * invq + betq);
    qout[(qb + (h0 + 1) * 256 + (w0 + 1) * 16 + z) * NC + c] = (f16)(aq11 * invq + betq);
    if ((z & 1) == 0) {
      const size_t t = (size_t)b * 512 + (th * 8 + tw) * 8 + (z >> 1);
      kout[t * NC + c] = (f16)(ak * invk + betk);
      vout[t * NC + c] = (f16)(av * invv + betv);
    }
  }
}

// ---------------- GEMM: C[M,384] = A[M,384] * W[384,384]^T ----------------
template<int MODE>
__global__ __launch_bounds__(256) void gemm_bt(
    const f16* __restrict__ A, const f16* __restrict__ Bw,
    void* __restrict__ Cout, const float* __restrict__ bias)
{
  const int LDT = 72;
  __shared__ f16 As[128 * 72];
  __shared__ f16 Bs[128 * 72];
  const int tid = threadIdx.x;
  const int w = tid >> 6, lane = tid & 63;
  const int g = lane >> 4, q = lane & 15;
  const int wr = w >> 1, wc = w & 1;
  const size_t brow = (size_t)blockIdx.y * 128;
  const int bcol = blockIdx.x * 128;
  f32x4 acc[4][4] = {};
  for (int kt = 0; kt < 6; ++kt) {
    const int k0 = kt * 64;
    __syncthreads();
#pragma unroll
    for (int i = tid; i < 1024; i += 256) {
      const int row = i >> 3, blk = i & 7;
      *(f16x8*)&As[row * LDT + blk * 8] = *(const f16x8*)&A[(brow + row) * NC + k0 + blk * 8];
      *(f16x8*)&Bs[row * LDT + blk * 8] = *(const f16x8*)&Bw[((size_t)bcol + row) * NC + k0 + blk * 8];
    }
    __syncthreads();
#pragma unroll
    for (int ks = 0; ks < 2; ++ks) {
      f16x8 af[4], bfr[4];
#pragma unroll
      for (int m = 0; m < 4; ++m) {
        af[m]  = *(const f16x8*)&As[(wr * 64 + m * 16 + q) * LDT + (4 * ks + g) * 8];
        bfr[m] = *(const f16x8*)&Bs[(wc * 64 + m * 16 + q) * LDT + (4 * ks + g) * 8];
      }
#pragma unroll
      for (int m = 0; m < 4; ++m)
#pragma unroll
        for (int n = 0; n < 4; ++n)
          acc[m][n] = MFMA16(af[m], bfr[n], acc[m][n]);
    }
  }
  float bvals[4];
  if (MODE == 2) {
#pragma unroll
    for (int n = 0; n < 4; ++n) bvals[n] = bias[bcol + wc * 64 + n * 16 + q];
  }
#pragma unroll
  for (int m = 0; m < 4; ++m) {
#pragma unroll
    for (int n = 0; n < 4; ++n) {
#pragma unroll
      for (int r = 0; r < 4; ++r) {
        const size_t row = brow + wr * 64 + m * 16 + 4 * g + r;
        const int col = bcol + wc * 64 + n * 16 + q;
        const float v = acc[m][n][r];
        if (MODE == 0) {
          ((f16*)Cout)[row * NC + col] = (f16)v;
        } else if (MODE == 1) {
          const size_t bi = row >> 9, t = row & 511;
          ((f16*)Cout)[(bi * NC + col) * 512 + t] = (f16)v;
        } else {
          ((float*)Cout)[row * NC + col] = v + bvals[n];
        }
      }
    }
  }
}

// ---------------- flash attention (LDS P round-trip) ----------------
__global__ __launch_bounds__(512) void attn(
    const f16* __restrict__ Qp, const f16* __restrict__ Kp,
    const f16* __restrict__ Vt, f16* __restrict__ O)
{
  const int LK = 72;
  const int LV = 136;
  const int LP = 136;
  __shared__ f16 Ks[128 * 72];
  __shared__ f16 Vs[64 * 136];
  __shared__ f16 Ps[8 * 16 * 136];
  const int tid = threadIdx.x;
  const int w = tid >> 6, lane = tid & 63;
  const int g = lane >> 4, q = lane & 15;
  const int qt = blockIdx.x, h = blockIdx.y, b = blockIdx.z;
  const float sc = 0.051031036307982884f * 1.4426950408889634f;
  const size_t qrow0 = (size_t)b * 4096 + qt * 128 + w * 16;
  f16x8 qf[2];
#pragma unroll
  for (int ks = 0; ks < 2; ++ks)
    qf[ks] = *(const f16x8*)(Qp + (qrow0 + q) * NC + h * 64 + ks * 32 + g * 8);
  f32x4 oa[4] = {};
  float m_run = -INFINITY, l_run = 0.f;
  for (int ch = 0; ch < 4; ++ch) {
    const size_t kb = (size_t)b * 512 + ch * 128;
    __syncthreads();
#pragma unroll
    for (int i = tid; i < 1024; i += 512) {
      const int j = i >> 3, blk = i & 7;
      *(f16x8*)&Ks[j * LK + blk * 8] = *(const f16x8*)&Kp[(kb + j) * NC + h * 64 + blk * 8];
    }
#pragma unroll
    for (int i = tid; i < 1024; i += 512) {
      const int dh = i >> 4, blk = i & 15;
      *(f16x8*)&Vs[dh * LV + blk * 8] =
          *(const f16x8*)&Vt[((size_t)b * NC + h * 64 + dh) * 512 + ch * 128 + blk * 8];
    }
    __syncthreads();
    f32x4 st[8] = {};
#pragma unroll
    for (int ks = 0; ks < 2; ++ks) {
#pragma unroll
      for (int m = 0; m < 8; ++m) {
        const f16x8 kf = *(const f16x8*)&Ks[(m * 16 + q) * LK + (4 * ks + g) * 8];
        st[m] = MFMA16(kf, qf[ks], st[m]);
      }
    }
    float tv[8][4];
    float cmax = -INFINITY;
#pragma unroll
    for (int m = 0; m < 8; ++m)
#pragma unroll
      for (int r = 0; r < 4; ++r) { tv[m][r] = st[m][r] * sc; cmax = fmaxf(cmax, tv[m][r]); }
    cmax = fmaxf(cmax, __shfl_xor(cmax, 16));
    cmax = fmaxf(cmax, __shfl_xor(cmax, 32));
    const float mnew = fmaxf(m_run, cmax);
    const float fac = exp2f(m_run - mnew);
    float psum = 0.f;
#pragma unroll
    for (int m = 0; m < 8; ++m) {
      const float p0 = exp2f(tv[m][0] - mnew), p1 = exp2f(tv[m][1] - mnew);
      const float p2 = exp2f(tv[m][2] - mnew), p3 = exp2f(tv[m][3] - mnew);
      psum += (p0 + p1) + (p2 + p3);
      f16* pr = &Ps[(w * 16 + q) * LP + m * 16 + 4 * g];
      pr[0] = (f16)p0; pr[1] = (f16)p1; pr[2] = (f16)p2; pr[3] = (f16)p3;
    }
    psum += __shfl_xor(psum, 16);
    psum += __shfl_xor(psum, 32);
    l_run = l_run * fac + psum;
    m_run = mnew;
#pragma unroll
    for (int r = 0; r < 4; ++r) {
      const float fr = __shfl(fac, g * 4 + r);
#pragma unroll
      for (int n = 0; n < 4; ++n) oa[n][r] *= fr;
    }
    __syncthreads();
#pragma unroll
    for (int ks = 0; ks < 4; ++ks) {
      const f16x8 pa = *(const f16x8*)&Ps[(w * 16 + q) * LP + ks * 32 + g * 8];
#pragma unroll
      for (int n = 0; n < 4; ++n) {
        const f16x8 vf = *(const f16x8*)&Vs[(n * 16 + q) * LV + ks * 32 + g * 8];
        oa[n] = MFMA16(pa, vf, oa[n]);
      }
    }
  }
  const float linv = 1.0f / l_run;
#pragma unroll
  for (int r = 0; r < 4; ++r) {
    const float lr = __shfl(linv, g * 4 + r);
    const size_t row = qrow0 + 4 * g + r;
#pragma unroll
    for (int n = 0; n < 4; ++n)
      O[row * NC + h * 64 + n * 16 + q] = (f16)(oa[n][r] * lr);
  }
}

// ---------------- launch ----------------
extern "C" void kernel_launch(void* const* d_in, const int* in_sizes, int n_in,
                              void* d_out, int out_size, void* d_ws, size_t ws_size,
                              hipStream_t stream) {
  const float* x   = (const float*)d_in[0];
  const float* cqw = (const float*)d_in[1];
  const float* ckw = (const float*)d_in[2];
  const float* cvw = (const float*)d_in[3];
  const float* bqg = (const float*)d_in[4],  *bqb = (const float*)d_in[5];
  const float* bqm = (const float*)d_in[6],  *bqv = (const float*)d_in[7];
  const float* bkg = (const float*)d_in[8],  *bkb = (const float*)d_in[9];
  const float* bkm = (const float*)d_in[10], *bkv = (const float*)d_in[11];
  const float* bvg = (const float*)d_in[12], *bvb = (const float*)d_in[13];
  const float* bvm = (const float*)d_in[14], *bvv = (const float*)d_in[15];
  const float* wq = (const float*)d_in[16];
  const float* wk = (const float*)d_in[17];
  const float* wv = (const float*)d_in[18];
  const float* pw = (const float*)d_in[19];
  const float* pb = (const float*)d_in[20];

  f16* q_tok = (f16*)d_out;                              // 25,165,824 B (lo half)
  f16* Qp    = (f16*)((char*)d_out + 25165824);          // 25,165,824 B (hi half)

  char* ws = (char*)d_ws;
  f16* wq_h  = (f16*)(ws + 0);
  f16* wk_h  = (f16*)(ws + 294912);
  f16* wv_h  = (f16*)(ws + 589824);
  f16* pw_h  = (f16*)(ws + 884736);
  f16* k_tok = (f16*)(ws + 1179648);
  f16* v_tok = (f16*)(ws + 4325376);
  f16* Kp    = (f16*)(ws + 7471104);
  f16* Vt    = (f16*)(ws + 10616832);
  f16* Oi    = (f16*)(ws + 13762560);   // ws total 38,928,384 B

  cvt_w<<<dim3(576), dim3(256), 0, stream>>>(wq, wk, wv, pw, wq_h, wk_h, wv_h, pw_h, 147456);
  conv_fused<<<dim3(64, 8), dim3(384), 0, stream>>>(
      x, cqw, ckw, cvw,
      bqg, bqb, bqm, bqv, bkg, bkb, bkm, bkv, bvg, bvb, bvm, bvv,
      q_tok, k_tok, v_tok);
  gemm_bt<0><<<dim3(3, 256), dim3(256), 0, stream>>>(q_tok, wq_h, Qp, nullptr);
  gemm_bt<0><<<dim3(3, 32),  dim3(256), 0, stream>>>(k_tok, wk_h, Kp, nullptr);
  gemm_bt<1><<<dim3(3, 32),  dim3(256), 0, stream>>>(v_tok, wv_h, Vt, nullptr);
  attn<<<dim3(32, 6, 8), dim3(512), 0, stream>>>(Qp, Kp, Vt, Oi);
  gemm_bt<2><<<dim3(3, 256), dim3(256), 0, stream>>>(Oi, pw_h, d_out, pb);
}